// Round 1
// baseline (561.191 us; speedup 1.0000x reference)
//
#include <hip/hip_runtime.h>

// out[b, w, j] = sum_p x[b,j,p] * weight[j,p,w] + bias[j,w]
// x: [B, M, P] f32, weight: [M, P, W] f32, bias: [M, W] f32, out: [B, W, M] f32
// B=128, M=10000, P=64, W=24. Memory-bound: ~513 MB min traffic -> ~81us floor.

constexpr int B = 128;
constexpr int M = 10000;
constexpr int P = 64;
constexpr int W = 24;

constexpr int JT  = 16;       // j-tile per block
constexpr int NT  = JT * W;   // 384 threads: thread owns one (j, w)
constexpr int BCH = 4;        // batch b's between barriers

__global__ __launch_bounds__(NT, 3) void pcl_kernel(
    const float* __restrict__ x, const float* __restrict__ wgt,
    const float* __restrict__ bias, float* __restrict__ out) {
  // padded to 25: 25*j mod 32 distinct for j=0..15 -> conflict-free transpose read
  __shared__ float lds_out[BCH][JT][W + 1];

  const int t  = threadIdx.x;
  const int j0 = blockIdx.x * JT;

  // compute mapping: w fastest -> 24 lanes share one j (x loads dedup to ~3 addrs/wave)
  const int jl = t / W;
  const int w  = t - jl * W;
  const int j  = j0 + jl;

  // weight[j, :, w] -> 64 registers, loaded once, reused across all 128 b
  float wr[P];
  {
    const float* wp = wgt + (size_t)j * (P * W) + w;
#pragma unroll
    for (int p = 0; p < P; ++p) wr[p] = wp[(size_t)p * W];
  }
  const float bs = bias[(size_t)j * W + w];

  // store mapping: j fastest -> 16 lanes write 64B contiguous
  const int ws = t / JT;  // 0..23
  const int js = t - ws * JT;  // 0..15
  const size_t out_col = (size_t)ws * M + (size_t)(j0 + js);

  for (int bb = 0; bb < B; bb += BCH) {
    float acc[BCH];
#pragma unroll
    for (int bc = 0; bc < BCH; ++bc) {
      const float4* xp =
          reinterpret_cast<const float4*>(x + ((size_t)(bb + bc) * M + j) * P);
      float a = bs;
#pragma unroll
      for (int q = 0; q < P / 4; ++q) {
        float4 xv = xp[q];
        a = fmaf(xv.x, wr[4 * q + 0], a);
        a = fmaf(xv.y, wr[4 * q + 1], a);
        a = fmaf(xv.z, wr[4 * q + 2], a);
        a = fmaf(xv.w, wr[4 * q + 3], a);
      }
      acc[bc] = a;
    }
    __syncthreads();  // previous iteration's lds_out reads done
#pragma unroll
    for (int bc = 0; bc < BCH; ++bc) lds_out[bc][jl][w] = acc[bc];
    __syncthreads();  // writes visible
#pragma unroll
    for (int bc = 0; bc < BCH; ++bc) {
      out[(size_t)(bb + bc) * (W * M) + out_col] = lds_out[bc][js][ws];
    }
  }
}

extern "C" void kernel_launch(void* const* d_in, const int* in_sizes, int n_in,
                              void* d_out, int out_size, void* d_ws, size_t ws_size,
                              hipStream_t stream) {
  const float* x    = (const float*)d_in[0];
  const float* wgt  = (const float*)d_in[1];
  const float* bias = (const float*)d_in[2];
  float* out        = (float*)d_out;

  dim3 grid(M / JT);  // 625
  dim3 block(NT);     // 384
  hipLaunchKernelGGL(pcl_kernel, grid, block, 0, stream, x, wgt, bias, out);
}

// Round 2
// 428.612 us; speedup vs baseline: 1.3093x; 1.3093x over previous
//
#include <hip/hip_runtime.h>

// out[b, w, j] = sum_p x[b,j,p] * weight[j,p,w] + bias[j,w]
// x: [B, M, P] f32, weight: [M, P, W] f32, bias: [M, W] f32, out: [B, W, M] f32
// B=128, M=10000, P=64, W=24. Memory-bound: ~513 MB min traffic -> ~81us floor.

constexpr int B = 128;
constexpr int M = 10000;
constexpr int P = 64;
constexpr int W = 24;

constexpr int JT  = 16;       // j-tile per block
constexpr int NT  = JT * W;   // 384 threads: thread owns one (j, w)
constexpr int BT  = 32;       // b's per block (B/BT = 4 blocks along b)
constexpr int BCH = 4;        // b's between barriers
constexpr int PAD = W + 2;    // stride 26: <=2-way conflicts on both phases

__global__ __launch_bounds__(NT, 2) void pcl_kernel(
    const float* __restrict__ x, const float* __restrict__ wgt,
    const float* __restrict__ bias, float* __restrict__ out) {
  __shared__ float lds_out[BCH][JT][PAD];

  const int t  = threadIdx.x;
  const int j0 = blockIdx.x * JT;
  const int b0 = blockIdx.y * BT;

  // compute mapping: w fastest -> 24 lanes share one j's x row
  const int jl = t / W;
  const int w  = t - jl * W;
  const int j  = j0 + jl;

  // weight[j, :, w] -> 16 float4 = 64 VGPRs, loaded once per block.
  // asm touch prevents the compiler from demoting/rematerializing (round-1:
  // VGPR=52 showed wr was reloaded from cache inside the hot loop).
  float4 wr[P / 4];
  {
    const float* wp = wgt + (size_t)j * (P * W) + w;
#pragma unroll
    for (int q = 0; q < P / 4; ++q) {
      wr[q].x = wp[(size_t)(4 * q + 0) * W];
      wr[q].y = wp[(size_t)(4 * q + 1) * W];
      wr[q].z = wp[(size_t)(4 * q + 2) * W];
      wr[q].w = wp[(size_t)(4 * q + 3) * W];
      asm volatile("" : "+v"(wr[q].x), "+v"(wr[q].y), "+v"(wr[q].z),
                        "+v"(wr[q].w));
    }
  }
  const float bs = bias[(size_t)j * W + w];

  // store mapping: one float4 of consecutive j per thread, fully coalesced
  const int sbc = t / (W * 4);            // 0..3   (which b in chunk)
  const int rem = t - sbc * (W * 4);      // 0..95
  const int sw  = rem / 4;                // 0..23  (which w)
  const int jq  = rem - sw * 4;           // 0..3   (which j-quad)

  for (int bb = 0; bb < BT; bb += BCH) {
    float acc[BCH];
#pragma unroll
    for (int bc = 0; bc < BCH; ++bc) {
      const float4* xp = reinterpret_cast<const float4*>(
          x + ((size_t)(b0 + bb + bc) * M + j) * P);
      float a = bs;
#pragma unroll
      for (int q = 0; q < P / 4; ++q) {
        float4 xv = xp[q];
        a = fmaf(xv.x, wr[q].x, a);
        a = fmaf(xv.y, wr[q].y, a);
        a = fmaf(xv.z, wr[q].z, a);
        a = fmaf(xv.w, wr[q].w, a);
      }
      acc[bc] = a;
    }
    __syncthreads();  // previous iteration's lds_out reads done
#pragma unroll
    for (int bc = 0; bc < BCH; ++bc) lds_out[bc][jl][w] = acc[bc];
    __syncthreads();  // writes visible
    float4 o;
    o.x = lds_out[sbc][4 * jq + 0][sw];
    o.y = lds_out[sbc][4 * jq + 1][sw];
    o.z = lds_out[sbc][4 * jq + 2][sw];
    o.w = lds_out[sbc][4 * jq + 3][sw];
    *reinterpret_cast<float4*>(
        out + ((size_t)(b0 + bb + sbc) * W + sw) * M + j0 + 4 * jq) = o;
  }
}

extern "C" void kernel_launch(void* const* d_in, const int* in_sizes, int n_in,
                              void* d_out, int out_size, void* d_ws, size_t ws_size,
                              hipStream_t stream) {
  const float* x    = (const float*)d_in[0];
  const float* wgt  = (const float*)d_in[1];
  const float* bias = (const float*)d_in[2];
  float* out        = (float*)d_out;

  dim3 grid(M / JT, B / BT);  // (625, 4)
  dim3 block(NT);             // 384
  hipLaunchKernelGGL(pcl_kernel, grid, block, 0, stream, x, wgt, bias, out);
}

// Round 3
// 397.448 us; speedup vs baseline: 1.4120x; 1.0784x over previous
//
#include <hip/hip_runtime.h>

// out[b, w, j] = sum_p x[b,j,p] * weight[j,p,w] + bias[j,w]
// x: [B, M, P] f32, weight: [M, P, W] f32, bias: [M, W] f32, out: [B, W, M] f32
// B=128, M=10000, P=64, W=24. Memory-bound: ~513 MB min traffic -> ~81us floor.
//
// Round-3 design: weight tile lives in LDS as bf16 (allocator refuses 64 live
// VGPRs/thread; LDS read is ~6cyc vs scratch ~180cyc). 768 threads, 64 KiB LDS
// -> 2 blocks/CU = 24 waves/CU. Weight staged once/block, x read once (24-lane
// broadcast), stores LDS-transposed to 64B-contiguous float4.

constexpr int B = 128;
constexpr int M = 10000;
constexpr int P = 64;
constexpr int W = 24;

constexpr int JT   = 16;          // j-tile per block
constexpr int BG   = 2;           // b-halves within block
constexpr int BCH  = 4;           // b's per inner group
constexpr int NT   = 384 * BG;    // 768 threads = 12 waves
constexpr int BBLK = 32;          // b's per block
constexpr int WPAD = 68;          // bf16 p-stride: 136B rows, 8B-aligned, 4-way max

__global__ __launch_bounds__(NT, 6) void pcl_kernel(
    const float* __restrict__ x, const float* __restrict__ wgt,
    const float* __restrict__ bias, float* __restrict__ out) {
  __shared__ unsigned short wlds[JT * W * WPAD];      // [jl][w][p] bf16: 52,224 B
  __shared__ float olds[BG][BCH][JT][W + 2];          // 13,312 B  (total 65,536)

  const int t  = threadIdx.x;
  const int j0 = blockIdx.x * JT;
  const int b0 = blockIdx.y * BBLK;

  // ---- stage weight[j0:j0+16,:,:] -> LDS bf16, transposed to [j][w][p] ----
  {
    const float4* wg4 = reinterpret_cast<const float4*>(wgt + (size_t)j0 * (P * W));
#pragma unroll
    for (int k = 0; k < (JT * P * W / 4) / NT; ++k) {  // 8 float4 per thread
      int f4 = t + k * NT;
      float4 v = wg4[f4];                 // fully coalesced
      int jl = f4 / (P * W / 4);          // 384 float4 per j
      int rr = f4 - jl * (P * W / 4);
      int p  = rr / 6;
      int w4 = (rr - p * 6) * 4;
      float vv[4] = {v.x, v.y, v.z, v.w};
#pragma unroll
      for (int i = 0; i < 4; ++i) {
        unsigned u = __float_as_uint(vv[i]);
        unsigned short h =
            (unsigned short)((u + 0x7fffu + ((u >> 16) & 1u)) >> 16);  // RNE
        wlds[(jl * W + w4 + i) * WPAD + p] = h;
      }
    }
  }

  // compute mapping: thread = (bg, jl, w); 24 w-lanes share one j's x row
  const int bg = t / 384;
  const int r  = t - bg * 384;
  const int jl = r / W;
  const int w  = r - jl * W;
  const unsigned short* wrow = &wlds[(size_t)(jl * W + w) * WPAD];
  const float bs = bias[(size_t)(j0 + jl) * W + w];

  // store mapping: one float4 (4 consecutive j) per thread -> 64B segments
  const int jq  = t & 3;
  const int ws  = (t >> 2) % W;
  const int r2  = t / (4 * W);   // 0..7
  const int bcs = r2 & 3;
  const int bgs = r2 >> 2;

  __syncthreads();

  for (int g = 0; g < BBLK / (BG * BCH); ++g) {  // 4 groups
    const int bb = b0 + bg * (BBLK / BG) + g * BCH;
    float acc0 = bs, acc1 = bs, acc2 = bs, acc3 = bs;
    const float4* xp0 = reinterpret_cast<const float4*>(x + ((size_t)(bb + 0) * M + j0 + jl) * P);
    const float4* xp1 = reinterpret_cast<const float4*>(x + ((size_t)(bb + 1) * M + j0 + jl) * P);
    const float4* xp2 = reinterpret_cast<const float4*>(x + ((size_t)(bb + 2) * M + j0 + jl) * P);
    const float4* xp3 = reinterpret_cast<const float4*>(x + ((size_t)(bb + 3) * M + j0 + jl) * P);
#pragma unroll
    for (int q = 0; q < P / 4; ++q) {
      uint2 wv = *reinterpret_cast<const uint2*>(wrow + 4 * q);  // ds_read_b64
      float w0 = __uint_as_float(wv.x << 16);
      float w1 = __uint_as_float(wv.x & 0xffff0000u);
      float w2 = __uint_as_float(wv.y << 16);
      float w3 = __uint_as_float(wv.y & 0xffff0000u);
      float4 a = xp0[q];
      float4 b = xp1[q];
      float4 c = xp2[q];
      float4 d = xp3[q];
      acc0 = fmaf(a.x, w0, acc0); acc0 = fmaf(a.y, w1, acc0);
      acc0 = fmaf(a.z, w2, acc0); acc0 = fmaf(a.w, w3, acc0);
      acc1 = fmaf(b.x, w0, acc1); acc1 = fmaf(b.y, w1, acc1);
      acc1 = fmaf(b.z, w2, acc1); acc1 = fmaf(b.w, w3, acc1);
      acc2 = fmaf(c.x, w0, acc2); acc2 = fmaf(c.y, w1, acc2);
      acc2 = fmaf(c.z, w2, acc2); acc2 = fmaf(c.w, w3, acc2);
      acc3 = fmaf(d.x, w0, acc3); acc3 = fmaf(d.y, w1, acc3);
      acc3 = fmaf(d.z, w2, acc3); acc3 = fmaf(d.w, w3, acc3);
    }
    __syncthreads();  // also guarantees prior g's olds reads are done
    olds[bg][0][jl][w] = acc0;
    olds[bg][1][jl][w] = acc1;
    olds[bg][2][jl][w] = acc2;
    olds[bg][3][jl][w] = acc3;
    __syncthreads();
    float4 o;
    o.x = olds[bgs][bcs][4 * jq + 0][ws];
    o.y = olds[bgs][bcs][4 * jq + 1][ws];
    o.z = olds[bgs][bcs][4 * jq + 2][ws];
    o.w = olds[bgs][bcs][4 * jq + 3][ws];
    *reinterpret_cast<float4*>(
        out + ((size_t)(b0 + bgs * (BBLK / BG) + g * BCH + bcs) * W + ws) * M +
        j0 + 4 * jq) = o;
  }
}

extern "C" void kernel_launch(void* const* d_in, const int* in_sizes, int n_in,
                              void* d_out, int out_size, void* d_ws, size_t ws_size,
                              hipStream_t stream) {
  const float* x    = (const float*)d_in[0];
  const float* wgt  = (const float*)d_in[1];
  const float* bias = (const float*)d_in[2];
  float* out        = (float*)d_out;

  dim3 grid(M / JT, B / BBLK);  // (625, 4) = 2500 blocks
  dim3 block(NT);               // 768
  hipLaunchKernelGGL(pcl_kernel, grid, block, 0, stream, x, wgt, bias, out);
}

// Round 4
// 188.020 us; speedup vs baseline: 2.9847x; 2.1139x over previous
//
#include <hip/hip_runtime.h>

// out[b, w, j] = sum_p x[b,j,p] * weight[j,p,w] + bias[j,w]
// x: [B, M, P] f32, weight: [M, P, W] f32, bias: [M, W] f32, out: [B, W, M] f32
// B=128, M=10000, P=64, W=24. Memory-bound: ~513 MB min traffic -> ~81us floor.
//
// Round-4: wave = one j, lane = one b. Each lane streams its own 256B x row
// (16 independent float4 -> 4 sectors in flight/wave -> high MLP). Weights in
// LDS fp32, read wave-uniform (broadcast, conflict-free). 24 fp32 accs/thread.
// Stores LDS-transposed to full-64B sector runs. No tight launch_bounds cap
// (round-3's 40-VGPR cap caused scratch spills: WRITE_SIZE 120->210 MB).

constexpr int B = 128;
constexpr int M = 10000;
constexpr int P = 64;
constexpr int W = 24;

constexpr int JT = 16;        // j's per block = waves per block
constexpr int BH = 64;        // b's per block
constexpr int NT = JT * 64;   // 1024 threads
constexpr int JP = 17;        // obuf j-dim pad

__global__ __launch_bounds__(NT, 4) void pcl_kernel(
    const float* __restrict__ x, const float* __restrict__ wgt,
    const float* __restrict__ bias, float* __restrict__ out) {
  __shared__ float wlds[JT * P * W];   // [j][p][w] fp32: 96 KiB (== global layout)
  __shared__ float obuf[W][16][JP];    // [w][b16][j] fp32: 25.5 KiB

  const int t  = threadIdx.x;
  const int j0 = blockIdx.x * JT;
  const int b0 = blockIdx.y * BH;

  // ---- stage weight tile: straight coalesced float4 copy (layouts match) ----
  {
    const float4* wg4 =
        reinterpret_cast<const float4*>(wgt + (size_t)j0 * (P * W));
    float4* wl4 = reinterpret_cast<float4*>(wlds);
#pragma unroll
    for (int k = 0; k < (JT * P * W / 4) / NT; ++k)  // 6 float4 per thread
      wl4[t + k * NT] = wg4[t + k * NT];
  }

  const int jw = t >> 6;   // wave index = local j
  const int b  = t & 63;   // lane = local b
  const int j  = j0 + jw;

  // bias row j -> 24 accumulators (6 float4, wave-broadcast addresses)
  float acc[W];
  {
    const float4* bp = reinterpret_cast<const float4*>(bias + (size_t)j * W);
#pragma unroll
    for (int q = 0; q < W / 4; ++q) {
      float4 v = bp[q];
      acc[4 * q + 0] = v.x; acc[4 * q + 1] = v.y;
      acc[4 * q + 2] = v.z; acc[4 * q + 3] = v.w;
    }
  }

  // whole x row into registers: 16 independent global loads
  float4 xr[P / 4];
  {
    const float4* xp = reinterpret_cast<const float4*>(
        x + ((size_t)(b0 + b) * M + j) * P);
#pragma unroll
    for (int q = 0; q < P / 4; ++q) xr[q] = xp[q];
  }

  __syncthreads();  // weights staged

  // ---- compute: 1536 fma, weights broadcast from LDS ----
  const float* wj = wlds + jw * (P * W);
#pragma unroll
  for (int q = 0; q < P / 4; ++q) {
    const float xs0 = xr[q].x, xs1 = xr[q].y, xs2 = xr[q].z, xs3 = xr[q].w;
    const float* wp = wj + (size_t)(4 * q) * W;
#pragma unroll
    for (int w = 0; w < W; ++w) acc[w] = fmaf(xs0, wp[w], acc[w]);
#pragma unroll
    for (int w = 0; w < W; ++w) acc[w] = fmaf(xs1, wp[W + w], acc[w]);
#pragma unroll
    for (int w = 0; w < W; ++w) acc[w] = fmaf(xs2, wp[2 * W + w], acc[w]);
#pragma unroll
    for (int w = 0; w < W; ++w) acc[w] = fmaf(xs3, wp[3 * W + w], acc[w]);
  }

  // ---- store: 4 rounds over b-quarters, LDS transpose, 64B-run stores ----
  for (int r = 0; r < 4; ++r) {
    __syncthreads();  // previous round's drain reads complete
    if ((b >> 4) == r) {
      const int b16 = b & 15;
#pragma unroll
      for (int w = 0; w < W; ++w) obuf[w][b16][jw] = acc[w];
    }
    __syncthreads();  // obuf visible
#pragma unroll
    for (int it = 0; it < 2; ++it) {
      const int d = t + it * NT;
      if (d < 16 * W * 4) {  // 1536 float4 per round
        const int j4  = d & 3;           // which j-quad (float4 over j)
        const int w   = (d >> 2) % W;
        const int b16 = d / (4 * W);
        float4 o;
        o.x = obuf[w][b16][4 * j4 + 0];
        o.y = obuf[w][b16][4 * j4 + 1];
        o.z = obuf[w][b16][4 * j4 + 2];
        o.w = obuf[w][b16][4 * j4 + 3];
        *reinterpret_cast<float4*>(
            out + ((size_t)(b0 + 16 * r + b16) * W + w) * M + j0 + 4 * j4) = o;
      }
    }
  }
}

extern "C" void kernel_launch(void* const* d_in, const int* in_sizes, int n_in,
                              void* d_out, int out_size, void* d_ws, size_t ws_size,
                              hipStream_t stream) {
  const float* x    = (const float*)d_in[0];
  const float* wgt  = (const float*)d_in[1];
  const float* bias = (const float*)d_in[2];
  float* out        = (float*)d_out;

  dim3 grid(M / JT, B / BH);  // (625, 2) = 1250 blocks
  dim3 block(NT);             // 1024
  hipLaunchKernelGGL(pcl_kernel, grid, block, 0, stream, x, wgt, bias, out);
}